// Round 4
// baseline (74.147 us; speedup 1.0000x reference)
//
#include <hip/hip_runtime.h>

typedef __attribute__((ext_vector_type(4))) float f32x4;
typedef __attribute__((ext_vector_type(8))) short bf16x8;

// f32 -> bf16 round-to-nearest-even
__device__ inline unsigned short f2bf(float x) {
  unsigned u = __builtin_bit_cast(unsigned, x);
  u += 0x7fffu + ((u >> 16) & 1u);
  return (unsigned short)(u >> 16);
}

__device__ inline bf16x8 pack8(f32x4 lo, f32x4 hi) {
  bf16x8 r;
  r[0] = (short)f2bf(lo[0]); r[1] = (short)f2bf(lo[1]);
  r[2] = (short)f2bf(lo[2]); r[3] = (short)f2bf(lo[3]);
  r[4] = (short)f2bf(hi[0]); r[5] = (short)f2bf(hi[1]);
  r[6] = (short)f2bf(hi[2]); r[7] = (short)f2bf(hi[3]);
  return r;
}

__device__ inline bf16x8 cvt8(const float* __restrict__ p) {
  return pack8(*(const f32x4*)p, *(const f32x4*)(p + 4));
}

// fused_gemm: 64 blocks x 256 thr (4 waves). Block owns 32-token slab T0.
// Phase 1: e[32][128] = X_slab @ Wr^T + br   (Wr staged to LDS bf16, K-chunked)
// Phase 2: UVt[512][slab] = [W1r;W1c] @ e^T (+b1 on u-half) + in-block cvec.
__global__ __launch_bounds__(256) void fused_gemm_kernel(
    const float* __restrict__ X, const float* __restrict__ Wr,
    const float* __restrict__ br, const float* __restrict__ W1,
    const float* __restrict__ b1, const float* __restrict__ W2,
    float* __restrict__ UVt, float* __restrict__ cvec) {
  __shared__ unsigned short Ws[128][264];   // Wr K-chunk bf16 (row pad: 2-way banks)
  __shared__ unsigned short e_s[32][136];   // e slab bf16
  __shared__ float cvp[4][32];

  int tid = threadIdx.x, wave = tid >> 6, lane = tid & 63;
  int T0 = blockIdx.x * 32;
  int lr = lane & 15, kg = (lane >> 4) * 8;
  int strip = wave >> 1, nh = wave & 1;     // 16-token strip, 64-n half

  const float* xrow = X + (size_t)(T0 + strip * 16 + lr) * 768 + kg;
  f32x4 acc0 = {0,0,0,0}, acc1 = {0,0,0,0}, acc2 = {0,0,0,0}, acc3 = {0,0,0,0};

  for (int c = 0; c < 3; ++c) {
    __syncthreads();  // Ws reuse guard
    // stage Wr[0:128][c*256:+256] -> Ws (each element converted once)
#pragma unroll
    for (int i = 0; i < 16; ++i) {
      int base = (tid + 256 * i) * 8;       // elem idx in [0, 32768)
      int row = base >> 8, col = base & 255;
      const float* src = Wr + (size_t)row * 768 + c * 256 + col;
      *(bf16x8*)&Ws[row][col] = pack8(*(const f32x4*)src, *(const f32x4*)(src + 4));
    }
    __syncthreads();
#pragma unroll
    for (int s = 0; s < 8; ++s) {
      bf16x8 a = cvt8(xrow + c * 256 + s * 32);
      bf16x8 b0 = *(const bf16x8*)&Ws[nh * 64 + lr][s * 32 + kg];
      bf16x8 b1f = *(const bf16x8*)&Ws[nh * 64 + 16 + lr][s * 32 + kg];
      bf16x8 b2f = *(const bf16x8*)&Ws[nh * 64 + 32 + lr][s * 32 + kg];
      bf16x8 b3f = *(const bf16x8*)&Ws[nh * 64 + 48 + lr][s * 32 + kg];
      acc0 = __builtin_amdgcn_mfma_f32_16x16x32_bf16(a, b0, acc0, 0, 0, 0);
      acc1 = __builtin_amdgcn_mfma_f32_16x16x32_bf16(a, b1f, acc1, 0, 0, 0);
      acc2 = __builtin_amdgcn_mfma_f32_16x16x32_bf16(a, b2f, acc2, 0, 0, 0);
      acc3 = __builtin_amdgcn_mfma_f32_16x16x32_bf16(a, b3f, acc3, 0, 0, 0);
    }
  }

  int rb = (lane >> 4) * 4;
  {
    f32x4 accs[4] = {acc0, acc1, acc2, acc3};
#pragma unroll
    for (int t = 0; t < 4; ++t) {
      int n = nh * 64 + t * 16 + lr;
      float bias = br[n];
#pragma unroll
      for (int r = 0; r < 4; ++r)
        e_s[strip * 16 + rb + r][n] = f2bf(accs[t][r] + bias);
    }
  }
  __syncthreads();

  // Phase 2: wave owns m in [128*wave, 128*wave+128). B-frags cached in regs.
  bf16x8 bfr[2][4];
#pragma unroll
  for (int tt = 0; tt < 2; ++tt)
#pragma unroll
    for (int kk = 0; kk < 4; ++kk)
      bfr[tt][kk] = *(const bf16x8*)&e_s[tt * 16 + lr][kk * 32 + kg];

  int M0 = wave * 128;
  float p0 = 0.f, p1 = 0.f;
#pragma unroll
  for (int mt = 0; mt < 8; ++mt) {
    int m1 = M0 + mt * 16;
    const float* arow = (m1 < 256)
        ? W1 + (size_t)(m1 + lr) * 256 + kg
        : W1 + (size_t)(m1 - 256 + lr) * 256 + 128 + kg;
    f32x4 ac0 = {0,0,0,0}, ac1 = {0,0,0,0};
#pragma unroll
    for (int kk = 0; kk < 4; ++kk) {
      bf16x8 a = cvt8(arow + kk * 32);
      ac0 = __builtin_amdgcn_mfma_f32_16x16x32_bf16(a, bfr[0][kk], ac0, 0, 0, 0);
      ac1 = __builtin_amdgcn_mfma_f32_16x16x32_bf16(a, bfr[1][kk], ac1, 0, 0, 0);
    }
#pragma unroll
    for (int r = 0; r < 4; ++r) {
      int m = m1 + rb + r;
      float bias = (m < 256) ? b1[m] : 0.f;
      float w2v = W2[m & 255];
      float v0 = ac0[r] + bias;
      float v1 = ac1[r] + bias;
      UVt[(size_t)m * 2048 + T0 + lr] = v0;
      UVt[(size_t)m * 2048 + T0 + 16 + lr] = v1;
      p0 = fmaf(w2v, v0, p0);
      p1 = fmaf(w2v, v1, p1);
    }
  }
  p0 += __shfl_xor(p0, 16); p0 += __shfl_xor(p0, 32);
  p1 += __shfl_xor(p1, 16); p1 += __shfl_xor(p1, 32);
  if (lane < 16) { cvp[wave][lr] = p0; cvp[wave][16 + lr] = p1; }
  __syncthreads();
  if (tid < 64) {
    int h = tid >> 5, tok = tid & 31;
    cvec[h * 2048 + T0 + tok] = 0.5f * (cvp[2 * h][tok] + cvp[2 * h + 1][tok]);
  }
}

// Pairwise: 32x32 tile/block, 4 waves m-split (64 m each), [m][tok] LDS,
// 4x4/lane outer product; all-wave combine + all-wave mirrored writes.
__global__ __launch_bounds__(256, 2) void pairwise_kernel(
    const float* __restrict__ UVt, const float* __restrict__ W2,
    const float* __restrict__ cvec, const float* __restrict__ b2p,
    float* __restrict__ Out) {
  __shared__ float u_s[4][64][36];
  __shared__ float v_s[4][64][36];
  __shared__ float w2_s[256];
  __shared__ float cuv[64];

  int tid = threadIdx.x;
  int wave = tid >> 6, lane = tid & 63;
  int b = blockIdx.y;
  int p = blockIdx.x;
  int it = 0;
  while (p >= 32 - it) { p -= 32 - it; ++it; }
  int jt = it + p;

  int utok = b * 1024 + it * 32;
  int vtok = b * 1024 + jt * 32;

  w2_s[tid] = W2[tid];
  if (tid < 32) cuv[tid] = cvec[utok + tid];
  else if (tid < 64) cuv[tid] = cvec[2048 + vtok + (tid - 32)];
  __syncthreads();  // w2_s/cuv visible; main loop LDS is wave-private

  int mr = lane >> 3, tq = (lane & 7) * 4;
  int tx = lane & 7, ty = lane >> 3;
  float acc[4][4] = {{0,0,0,0},{0,0,0,0},{0,0,0,0},{0,0,0,0}};

  // stage this wave's 64-m slice
#pragma unroll
  for (int g = 0; g < 8; ++g) {
    int ml = g * 8 + mr;
    int m = wave * 64 + ml;
    *(f32x4*)&u_s[wave][ml][tq] = *(const f32x4*)(UVt + (size_t)m * 2048 + utok + tq);
    *(f32x4*)&v_s[wave][ml][tq] = *(const f32x4*)(UVt + (size_t)(256 + m) * 2048 + vtok + tq);
  }

  for (int ml = 0; ml < 64; ml += 4) {
    f32x4 wq = *(const f32x4*)&w2_s[wave * 64 + ml];
#pragma unroll
    for (int s = 0; s < 4; ++s) {
      f32x4 uu = *(const f32x4*)&u_s[wave][ml + s][4 * ty];
      f32x4 vv = *(const f32x4*)&v_s[wave][ml + s][4 * tx];
      float w = wq[s];
#pragma unroll
      for (int i = 0; i < 4; ++i)
#pragma unroll
        for (int j = 0; j < 4; ++j)
          acc[i][j] = fmaf(w, fabsf(uu[i] + vv[j]), acc[i][j]);
    }
  }

  // all-wave combine via LDS overlays
  float* ovp = (float*)u_s;   // [4][32][36] partials
  float* t2p = (float*)v_s;   // [32][36] transposed tile
  __syncthreads();            // all main-loop reads done before overlay writes
#pragma unroll
  for (int i = 0; i < 4; ++i) {
    f32x4 rv = {acc[i][0], acc[i][1], acc[i][2], acc[i][3]};
    *(f32x4*)&ovp[((size_t)wave * 32 + 4 * ty + i) * 36 + 4 * tx] = rv;
  }
  __syncthreads();

  int ly = lane >> 3, tc = lane & 7;   // row-within-wave, col group
  int row = wave * 8 + ly;
  float b2v = b2p[0];
  f32x4 sum = {0,0,0,0};
#pragma unroll
  for (int q = 0; q < 4; ++q) {
    f32x4 part = *(const f32x4*)&ovp[((size_t)q * 32 + row) * 36 + 4 * tc];
#pragma unroll
    for (int j = 0; j < 4; ++j) sum[j] += part[j];
  }
  float cu = cuv[row];
  f32x4 val;
#pragma unroll
  for (int j = 0; j < 4; ++j)
    val[j] = 0.5f * sum[j] + cu + cuv[32 + 4 * tc + j] + b2v;

  // write transposed copy for mirror
  *(f32x4*)&t2p[(size_t)row * 36 + 4 * tc] = val;

  size_t obase = (size_t)b << 20;
  int i0 = it * 32, j0 = jt * 32;
  if (it != jt)
    *(f32x4*)(Out + obase + (size_t)(i0 + row) * 1024 + j0 + 4 * tc) = val;
  else {
#pragma unroll
    for (int j = 0; j < 4; ++j) {
      int jl = 4 * tc + j;
      if (jl >= row) Out[obase + (size_t)(i0 + row) * 1024 + j0 + jl] = val[j];
    }
  }
  __syncthreads();  // t2p complete
  f32x4 mv;
#pragma unroll
  for (int j = 0; j < 4; ++j) mv[j] = t2p[(size_t)(4 * tc + j) * 36 + row];
  if (it != jt)
    *(f32x4*)(Out + obase + (size_t)(j0 + row) * 1024 + i0 + 4 * tc) = mv;
  else {
#pragma unroll
    for (int j = 0; j < 4; ++j) {
      int c = 4 * tc + j;
      if (row > c) Out[obase + (size_t)(i0 + row) * 1024 + j0 + c] = mv[j];
    }
  }
}

extern "C" void kernel_launch(void* const* d_in, const int* in_sizes, int n_in,
                              void* d_out, int out_size, void* d_ws, size_t ws_size,
                              hipStream_t stream) {
  (void)in_sizes; (void)n_in; (void)out_size; (void)ws_size;
  const float* X  = (const float*)d_in[0];
  const float* Wr = (const float*)d_in[1];
  const float* br = (const float*)d_in[2];
  const float* W1 = (const float*)d_in[3];
  const float* b1 = (const float*)d_in[4];
  const float* W2 = (const float*)d_in[5];
  const float* b2 = (const float*)d_in[6];
  float* Out = (float*)d_out;

  float* UVt  = (float*)d_ws;                                   // 512*2048*4 = 4 MiB
  float* cvec = (float*)((char*)d_ws + (size_t)512 * 2048 * 4); // 2*2048*4 = 16 KiB

  fused_gemm_kernel<<<64, 256, 0, stream>>>(X, Wr, br, W1, b1, W2, UVt, cvec);
  pairwise_kernel<<<dim3(528, 2), 256, 0, stream>>>(UVt, W2, cvec, b2, Out);
}

// Round 5
// 53.710 us; speedup vs baseline: 1.3805x; 1.3805x over previous
//
#include <hip/hip_runtime.h>

typedef __attribute__((ext_vector_type(4))) float f32x4;
typedef __attribute__((ext_vector_type(8))) short bf16x8;

// f32 -> bf16 round-to-nearest-even
__device__ inline unsigned short f2bf(float x) {
  unsigned u = __builtin_bit_cast(unsigned, x);
  u += 0x7fffu + ((u >> 16) & 1u);
  return (unsigned short)(u >> 16);
}

__device__ inline bf16x8 pack8(f32x4 lo, f32x4 hi) {
  bf16x8 r;
  r[0] = (short)f2bf(lo[0]); r[1] = (short)f2bf(lo[1]);
  r[2] = (short)f2bf(lo[2]); r[3] = (short)f2bf(lo[3]);
  r[4] = (short)f2bf(hi[0]); r[5] = (short)f2bf(hi[1]);
  r[6] = (short)f2bf(hi[2]); r[7] = (short)f2bf(hi[3]);
  return r;
}

// prep: X (768 blks) / Wr (48) / W1-split (32) -> bf16; zero cvec (1 blk)
__global__ __launch_bounds__(256) void prep_kernel(
    const float* __restrict__ X, const float* __restrict__ Wr,
    const float* __restrict__ W1,
    unsigned short* __restrict__ Xbf, unsigned short* __restrict__ Wrbf,
    unsigned short* __restrict__ W1bf, float* __restrict__ cvec) {
  int bid = blockIdx.x, tid = threadIdx.x;
  if (bid < 768) {
    size_t o = (size_t)bid * 2048 + tid * 8;
    *(bf16x8*)(Xbf + o) = pack8(*(const f32x4*)(X + o), *(const f32x4*)(X + o + 4));
  } else if (bid < 816) {
    size_t o = (size_t)(bid - 768) * 2048 + tid * 8;
    *(bf16x8*)(Wrbf + o) = pack8(*(const f32x4*)(Wr + o), *(const f32x4*)(Wr + o + 4));
  } else if (bid < 848) {
    size_t o = (size_t)(bid - 816) * 2048 + tid * 8;
    int m = (int)(o >> 7), k = (int)(o & 127);
    const float* src = (m < 256) ? (W1 + (size_t)m * 256 + k)
                                 : (W1 + (size_t)(m - 256) * 256 + 128 + k);
    *(bf16x8*)(W1bf + o) = pack8(*(const f32x4*)src, *(const f32x4*)(src + 4));
  } else {
    f32x4 z = {0.f, 0.f, 0.f, 0.f};
#pragma unroll
    for (int i = 0; i < 4; ++i)
      *(f32x4*)(cvec + tid * 16 + i * 4) = z;
  }
}

// GEMM1: e[2048][128] = X @ Wr^T + br (bf16 out). One 16x16 tile per wave,
// direct bf16 global loads (L2-resident), no LDS. 256 blocks, 1024 waves.
__global__ __launch_bounds__(256) void gemm1_kernel(
    const unsigned short* __restrict__ Xbf, const unsigned short* __restrict__ Wrbf,
    const float* __restrict__ br, unsigned short* __restrict__ Ebf) {
  int wave = threadIdx.x >> 6, lane = threadIdx.x & 63;
  int tok0 = (blockIdx.x * 4 + wave) * 16;
  int n0 = blockIdx.y * 16;
  int lr = lane & 15, kg = (lane >> 4) * 8;
  const unsigned short* ap = Xbf + (size_t)(tok0 + lr) * 768 + kg;
  const unsigned short* bp = Wrbf + (size_t)(n0 + lr) * 768 + kg;
  f32x4 acc = {0, 0, 0, 0};
#pragma unroll 6
  for (int k0 = 0; k0 < 768; k0 += 32) {
    bf16x8 a = *(const bf16x8*)(ap + k0);
    bf16x8 b = *(const bf16x8*)(bp + k0);
    acc = __builtin_amdgcn_mfma_f32_16x16x32_bf16(a, b, acc, 0, 0, 0);
  }
  int rb = (lane >> 4) * 4;
  float bias = br[n0 + lr];
#pragma unroll
  for (int r = 0; r < 4; ++r)
    Ebf[(size_t)(tok0 + rb + r) * 128 + n0 + lr] = f2bf(acc[r] + bias);
}

// GEMM2 + fused cvec: UVt[512][2048] (0..255 = e@W1r^T + b1, 256..511 = e@W1c^T)
// epilogue: cvec[h][tok] += 0.5*sum_m W2[m]*val via shfl-reduce + atomicAdd.
__global__ __launch_bounds__(256) void gemm2_kernel(
    const unsigned short* __restrict__ Ebf, const unsigned short* __restrict__ W1bf,
    const float* __restrict__ b1, const float* __restrict__ W2,
    float* __restrict__ UVt, float* __restrict__ cvec) {
  int wave = threadIdx.x >> 6, lane = threadIdx.x & 63;
  int t0 = blockIdx.x * 64;
  int m0 = (blockIdx.y * 4 + wave) * 16;
  int lr = lane & 15, kg = (lane >> 4) * 8;
  const unsigned short* aB = W1bf + (size_t)(m0 + lr) * 128 + kg;
  f32x4 acc[4] = {{0,0,0,0},{0,0,0,0},{0,0,0,0},{0,0,0,0}};
#pragma unroll
  for (int k0 = 0; k0 < 128; k0 += 32) {
    bf16x8 a = *(const bf16x8*)(aB + k0);
#pragma unroll
    for (int t = 0; t < 4; ++t) {
      bf16x8 b = *(const bf16x8*)(Ebf + (size_t)(t0 + t * 16 + lr) * 128 + kg + k0);
      acc[t] = __builtin_amdgcn_mfma_f32_16x16x32_bf16(a, b, acc[t], 0, 0, 0);
    }
  }
  int rb = (lane >> 4) * 4;
  float p[4] = {0.f, 0.f, 0.f, 0.f};
#pragma unroll
  for (int t = 0; t < 4; ++t) {
#pragma unroll
    for (int r = 0; r < 4; ++r) {
      int m = m0 + rb + r;
      float val = acc[t][r] + ((m0 < 256) ? b1[m] : 0.f);
      UVt[(size_t)m * 2048 + t0 + t * 16 + lr] = val;
      p[t] = fmaf(W2[m & 255], val, p[t]);
    }
  }
#pragma unroll
  for (int t = 0; t < 4; ++t) {
    p[t] += __shfl_xor(p[t], 16);
    p[t] += __shfl_xor(p[t], 32);
  }
  if (lane < 16) {
    int h = (m0 < 256) ? 0 : 1;
#pragma unroll
    for (int t = 0; t < 4; ++t)
      atomicAdd(&cvec[h * 2048 + t0 + t * 16 + lane], 0.5f * p[t]);
  }
}

// Pairwise: 32x32 tile/block, 4 waves m-split (64 m each), [m][tok] LDS,
// 4x4/lane outer product; all-wave combine + all-wave mirrored writes.
__global__ __launch_bounds__(256, 2) void pairwise_kernel(
    const float* __restrict__ UVt, const float* __restrict__ W2,
    const float* __restrict__ cvec, const float* __restrict__ b2p,
    float* __restrict__ Out) {
  __shared__ float u_s[4][64][36];
  __shared__ float v_s[4][64][36];
  __shared__ float w2_s[256];
  __shared__ float cuv[64];

  int tid = threadIdx.x;
  int wave = tid >> 6, lane = tid & 63;
  int b = blockIdx.y;
  int p = blockIdx.x;
  int it = 0;
  while (p >= 32 - it) { p -= 32 - it; ++it; }
  int jt = it + p;

  int utok = b * 1024 + it * 32;
  int vtok = b * 1024 + jt * 32;

  w2_s[tid] = W2[tid];
  if (tid < 32) cuv[tid] = cvec[utok + tid];
  else if (tid < 64) cuv[tid] = cvec[2048 + vtok + (tid - 32)];
  __syncthreads();  // w2_s/cuv visible; main loop LDS is wave-private

  int mr = lane >> 3, tq = (lane & 7) * 4;
  int tx = lane & 7, ty = lane >> 3;
  float acc[4][4] = {{0,0,0,0},{0,0,0,0},{0,0,0,0},{0,0,0,0}};

  // stage this wave's 64-m slice
#pragma unroll
  for (int g = 0; g < 8; ++g) {
    int ml = g * 8 + mr;
    int m = wave * 64 + ml;
    *(f32x4*)&u_s[wave][ml][tq] = *(const f32x4*)(UVt + (size_t)m * 2048 + utok + tq);
    *(f32x4*)&v_s[wave][ml][tq] = *(const f32x4*)(UVt + (size_t)(256 + m) * 2048 + vtok + tq);
  }

  for (int ml = 0; ml < 64; ml += 4) {
    f32x4 wq = *(const f32x4*)&w2_s[wave * 64 + ml];
#pragma unroll
    for (int s = 0; s < 4; ++s) {
      f32x4 uu = *(const f32x4*)&u_s[wave][ml + s][4 * ty];
      f32x4 vv = *(const f32x4*)&v_s[wave][ml + s][4 * tx];
      float w = wq[s];
#pragma unroll
      for (int i = 0; i < 4; ++i)
#pragma unroll
        for (int j = 0; j < 4; ++j)
          acc[i][j] = fmaf(w, fabsf(uu[i] + vv[j]), acc[i][j]);
    }
  }

  // all-wave combine via LDS overlays
  float* ovp = (float*)u_s;   // [4][32][36] partials
  float* t2p = (float*)v_s;   // [32][36] transposed tile
  __syncthreads();            // all main-loop reads done before overlay writes
#pragma unroll
  for (int i = 0; i < 4; ++i) {
    f32x4 rv = {acc[i][0], acc[i][1], acc[i][2], acc[i][3]};
    *(f32x4*)&ovp[((size_t)wave * 32 + 4 * ty + i) * 36 + 4 * tx] = rv;
  }
  __syncthreads();

  int ly = lane >> 3, tc = lane & 7;   // row-within-wave, col group
  int row = wave * 8 + ly;
  float b2v = b2p[0];
  f32x4 sum = {0, 0, 0, 0};
#pragma unroll
  for (int q = 0; q < 4; ++q) {
    f32x4 part = *(const f32x4*)&ovp[((size_t)q * 32 + row) * 36 + 4 * tc];
#pragma unroll
    for (int j = 0; j < 4; ++j) sum[j] += part[j];
  }
  float cu = cuv[row];
  f32x4 val;
#pragma unroll
  for (int j = 0; j < 4; ++j)
    val[j] = 0.5f * sum[j] + cu + cuv[32 + 4 * tc + j] + b2v;

  // write transposed copy for mirror
  *(f32x4*)&t2p[(size_t)row * 36 + 4 * tc] = val;

  size_t obase = (size_t)b << 20;
  int i0 = it * 32, j0 = jt * 32;
  if (it != jt)
    *(f32x4*)(Out + obase + (size_t)(i0 + row) * 1024 + j0 + 4 * tc) = val;
  else {
#pragma unroll
    for (int j = 0; j < 4; ++j) {
      int jl = 4 * tc + j;
      if (jl >= row) Out[obase + (size_t)(i0 + row) * 1024 + j0 + jl] = val[j];
    }
  }
  __syncthreads();  // t2p complete
  f32x4 mv;
#pragma unroll
  for (int j = 0; j < 4; ++j) mv[j] = t2p[(size_t)(4 * tc + j) * 36 + row];
  if (it != jt)
    *(f32x4*)(Out + obase + (size_t)(j0 + row) * 1024 + i0 + 4 * tc) = mv;
  else {
#pragma unroll
    for (int j = 0; j < 4; ++j) {
      int c = 4 * tc + j;
      if (row > c) Out[obase + (size_t)(i0 + row) * 1024 + j0 + c] = mv[j];
    }
  }
}

extern "C" void kernel_launch(void* const* d_in, const int* in_sizes, int n_in,
                              void* d_out, int out_size, void* d_ws, size_t ws_size,
                              hipStream_t stream) {
  (void)in_sizes; (void)n_in; (void)out_size; (void)ws_size;
  const float* X  = (const float*)d_in[0];
  const float* Wr = (const float*)d_in[1];
  const float* br = (const float*)d_in[2];
  const float* W1 = (const float*)d_in[3];
  const float* b1 = (const float*)d_in[4];
  const float* W2 = (const float*)d_in[5];
  const float* b2 = (const float*)d_in[6];
  float* Out = (float*)d_out;

  char* ws = (char*)d_ws;
  unsigned short* Xbf  = (unsigned short*)(ws);            // 3,145,728 B
  unsigned short* Wrbf = (unsigned short*)(ws + 3145728);  //   196,608 B
  unsigned short* W1bf = (unsigned short*)(ws + 3342336);  //   131,072 B
  unsigned short* Ebf  = (unsigned short*)(ws + 3473408);  //   524,288 B
  float*          UVt  = (float*)(ws + 3997696);           // 4,194,304 B
  float*          cvec = (float*)(ws + 8192000);           //    16,384 B

  prep_kernel<<<849, 256, 0, stream>>>(X, Wr, W1, Xbf, Wrbf, W1bf, cvec);
  gemm1_kernel<<<dim3(32, 8), 256, 0, stream>>>(Xbf, Wrbf, br, Ebf);
  gemm2_kernel<<<dim3(32, 8), 256, 0, stream>>>(Ebf, W1bf, b1, W2, UVt, cvec);
  pairwise_kernel<<<dim3(528, 2), 256, 0, stream>>>(UVt, W2, cvec, b2, Out);
}